// Round 16
// baseline (165.577 us; speedup 1.0000x reference)
//
#include <hip/hip_runtime.h>

#define SIDE 96
#define NN 9216            // SIDE*SIDE
#define BATCH 32
#define SPLIT 36           // split-K slices (partials 21.2 MB)
#define SLICE (NN / SPLIT) // 256
#define NKT (SLICE / 16)   // 16 k-tiles (K=16 each) per slice
#define NJB (NN / 256)     // 36 j-blocks (256 cols per 8-wave block)
#define PSTRIDE ((size_t)NN * BATCH)   // bf16 elems per partial slice

typedef __attribute__((ext_vector_type(8)))  short  short8;
typedef __attribute__((ext_vector_type(16))) float  f32x16;
typedef __attribute__((ext_vector_type(4)))  unsigned int uintx4;

__device__ __forceinline__ float clamp01(float v) {
    return fminf(fmaxf(v, 0.0f), 1.0f);
}

__device__ __forceinline__ unsigned short f2bf(float f) {  // RNE fp32->bf16
    unsigned int u = __float_as_uint(f);
    return (unsigned short)((u + 0x7fffu + ((u >> 16) & 1u)) >> 16);
}

__device__ __forceinline__ unsigned int packbf2(float a, float b) {
    return (unsigned int)f2bf(a) | ((unsigned int)f2bf(b) << 16);
}

__device__ __forceinline__ float bf2f(unsigned short u) {
    return __uint_as_float(((unsigned int)u) << 16);
}

// atf[kt][l][i] = bf16(x[b][k]),  k = kt*16 + (l>>5)*8 + i,  b = l&31.
// Exactly the MFMA B-fragment order: lane l, k-slot ((l>>5), i).
__global__ __launch_bounds__(256) void k_prep_x(const float* __restrict__ x,
                                                unsigned short* __restrict__ atf) {
    int o = blockIdx.x * 256 + threadIdx.x;   // over NN*BATCH
    int kt = o >> 9, r = o & 511, l = r >> 3, i = r & 7;
    int b = l & 31, g = l >> 5;
    int k = kt * 16 + g * 8 + i;
    atf[o] = f2bf(x[(size_t)b * NN + k]);
}

// Partial GEMM via MFMA: part[s][j][b] (bf16) = sum_{k in slice s} at[k][b]*W[k][j]
// 8-wave (512-thread) block covers 256 consecutive j -> 1 KB contiguous W
// read per k-row per block (DRAM row-buffer locality); all 8 waves share
// the identical atf dwordx4 loads via L1 broadcast.
// C/D mapping (verified): col(b)=lane&31, row(j)=(r&3)+8*(r>>2)+4*(lane>>5).
__global__ __launch_bounds__(512, 4) void k_gemm_mfma(
    const float* __restrict__ W,             // [NN][NN] k-major
    const unsigned short* __restrict__ atf,  // fragment-ordered activations
    unsigned short* __restrict__ part)       // [SPLIT][NN][BATCH] bf16
{
    const int tid  = threadIdx.x;
    const int wave = tid >> 6;               // 0..7
    const int lane = tid & 63;
    const int jl   = lane & 31;
    const int g    = lane >> 5;
    const int jb = blockIdx.x % NJB;
    const int s  = blockIdx.x / NJB;
    const int j  = jb * 256 + wave * 32 + jl;
    const size_t k0 = (size_t)s * SLICE;

    const float* wp = W + (k0 + (size_t)g * 8) * NN + j;
    const uintx4* bp = (const uintx4*)atf + (k0 >> 4) * 64 + lane;

    f32x16 acc;
#pragma unroll
    for (int e = 0; e < 16; ++e) acc[e] = 0.0f;

    float  wb[2][8];
    uintx4 bb[2];
#pragma unroll
    for (int i = 0; i < 8; ++i) wb[0][i] = wp[(size_t)i * NN];
    bb[0] = bp[0];

#pragma unroll
    for (int kt = 0; kt < NKT; ++kt) {
        const int cur = kt & 1, nxt = cur ^ 1;
        if (kt + 1 < NKT) {   // prefetch next k-tile (compile-time branch)
#pragma unroll
            for (int i = 0; i < 8; ++i)
                wb[nxt][i] = wp[((size_t)(kt + 1) * 16 + i) * NN];
            bb[nxt] = bp[(kt + 1) * 64];
        }
        uintx4 ap;
        ap[0] = packbf2(wb[cur][0], wb[cur][1]);
        ap[1] = packbf2(wb[cur][2], wb[cur][3]);
        ap[2] = packbf2(wb[cur][4], wb[cur][5]);
        ap[3] = packbf2(wb[cur][6], wb[cur][7]);
        short8 af = __builtin_bit_cast(short8, ap);
        short8 bf = __builtin_bit_cast(short8, bb[cur]);
        acc = __builtin_amdgcn_mfma_f32_32x32x16_bf16(af, bf, acc, 0, 0, 0);
    }

    unsigned short* pp = part + ((size_t)s * NN + (size_t)jb * 256 + wave * 32) * BATCH + jl;
#pragma unroll
    for (int r2 = 0; r2 < 16; ++r2) {
        int row = (r2 & 3) + 8 * (r2 >> 2) + 4 * g;
        pp[(size_t)row * BATCH] = f2bf(acc[r2]);
    }
}

// afft[k][b] = clamp01( sum_s part[s][k][b] ) (fp32), plus the same values
// re-emitted in MFMA B-fragment order (bf16) for the second GEMM.
// One thread handles 4 consecutive elements (same k, b0=4-aligned).
__global__ __launch_bounds__(256) void k_reduce_aff(
    const uint2* __restrict__ part,          // viewing bf16x4
    float* __restrict__ afft,
    unsigned short* __restrict__ atf2)
{
    int t = blockIdx.x * 256 + threadIdx.x;   // over NN*BATCH/4
    float v0 = 0.0f, v1 = 0.0f, v2 = 0.0f, v3 = 0.0f;
    for (int s = 0; s < SPLIT; ++s) {
        uint2 u = part[(size_t)s * (PSTRIDE / 4) + t];
        v0 += bf2f((unsigned short)(u.x & 0xffffu));
        v1 += bf2f((unsigned short)(u.x >> 16));
        v2 += bf2f((unsigned short)(u.y & 0xffffu));
        v3 += bf2f((unsigned short)(u.y >> 16));
    }
    v0 = clamp01(v0); v1 = clamp01(v1); v2 = clamp01(v2); v3 = clamp01(v3);
    float4 o = make_float4(v0, v1, v2, v3);
    ((float4*)afft)[t] = o;

    int k = t >> 3, b = (t & 7) * 4;
    int kt = k >> 4, g = (k >> 3) & 1, i = k & 7;
    size_t ob = (size_t)kt * 512 + (size_t)(g * 32 + b) * 8 + i;
    atf2[ob]      = f2bf(v0);
    atf2[ob + 8]  = f2bf(v1);
    atf2[ob + 16] = f2bf(v2);
    atf2[ob + 24] = f2bf(v3);
}

// Fused epilogue: reduce inhibitory bf16 partials (uint2 loads, 4 elems per
// thread), sparse excitatory gather (13 taps), combine. Thread = (j, b-quad).
__global__ __launch_bounds__(256) void k_combine(
    const uint2* __restrict__ part,           // [SPLIT][NN][BATCH] bf16, x4 view
    const float* __restrict__ afft,           // [NN][BATCH], clamped
    const float* __restrict__ We,             // [NN][NN]
    float* __restrict__ out)                  // [BATCH][NN]
{
    int t = blockIdx.x * 256 + threadIdx.x;   // over NN*BATCH/4
    int j  = t >> 3;
    int bq = t & 7;                           // batch quad: b = 4bq..4bq+3

    float i0 = 0.0f, i1 = 0.0f, i2 = 0.0f, i3 = 0.0f;
    for (int s = 0; s < SPLIT; ++s) {
        uint2 u = part[(size_t)s * (PSTRIDE / 4) + t];
        i0 += bf2f((unsigned short)(u.x & 0xffffu));
        i1 += bf2f((unsigned short)(u.x >> 16));
        i2 += bf2f((unsigned short)(u.y & 0xffffu));
        i3 += bf2f((unsigned short)(u.y >> 16));
    }
    i0 = clamp01(i0); i1 = clamp01(i1); i2 = clamp01(i2); i3 = clamp01(i3);

    int mx = j / SIDE;
    int my = j - mx * SIDE;

    const int dxs[13] = {-2,-1,-1,-1, 0, 0, 0, 0, 0, 1, 1, 1, 2};
    const int dys[13] = { 0,-1, 0, 1,-2,-1, 0, 1, 2,-1, 0, 1, 0};

    float e0 = 0.0f, e1 = 0.0f, e2 = 0.0f, e3 = 0.0f;
#pragma unroll
    for (int tp = 0; tp < 13; ++tp) {
        int xx = mx + dxs[tp];
        int yy = my + dys[tp];
        if ((unsigned)xx < SIDE && (unsigned)yy < SIDE) {
            int i = xx * SIDE + yy;
            float w = We[(size_t)i * NN + j];
            float4 av = ((const float4*)afft)[(size_t)i * 8 + bq];
            e0 = fmaf(av.x, w, e0);
            e1 = fmaf(av.y, w, e1);
            e2 = fmaf(av.z, w, e2);
            e3 = fmaf(av.w, w, e3);
        }
    }
    e0 = clamp01(e0); e1 = clamp01(e1); e2 = clamp01(e2); e3 = clamp01(e3);

    float4 a = ((const float4*)afft)[t];
    out[(size_t)(4 * bq + 0) * NN + j] = clamp01(a.x + 0.2f * e0 - 0.4f * i0);
    out[(size_t)(4 * bq + 1) * NN + j] = clamp01(a.y + 0.2f * e1 - 0.4f * i1);
    out[(size_t)(4 * bq + 2) * NN + j] = clamp01(a.z + 0.2f * e2 - 0.4f * i2);
    out[(size_t)(4 * bq + 3) * NN + j] = clamp01(a.w + 0.2f * e3 - 0.4f * i3);
}

extern "C" void kernel_launch(void* const* d_in, const int* in_sizes, int n_in,
                              void* d_out, int out_size, void* d_ws, size_t ws_size,
                              hipStream_t stream) {
    const float* x  = (const float*)d_in[0];  // [32][9216]
    const float* Wr = (const float*)d_in[1];  // [9216][9216]
    const float* We = (const float*)d_in[2];  // [9216][9216] sparse (radius 2)
    const float* Wi = (const float*)d_in[3];  // [9216][9216]
    float* out = (float*)d_out;               // [32][9216]

    unsigned short* atf1 = (unsigned short*)d_ws;        // NN*32 bf16 (frag order)
    float* afft = (float*)(atf1 + (size_t)NN * BATCH);   // NN*32 fp32
    unsigned short* atf2 = (unsigned short*)(afft + (size_t)NN * BATCH);
    unsigned short* part = atf2 + (size_t)NN * BATCH;    // SPLIT*NN*32 bf16 = 21.2 MB

    dim3 gblk(512);
    dim3 blk(256);
    dim3 grid_eb(NN * BATCH / 256);        // 1152
    dim3 grid_r4(NN * BATCH / 4 / 256);    // 288
    dim3 grid_gm(NJB * SPLIT);             // 1296

    k_prep_x    <<<grid_eb, blk, 0, stream>>>(x, atf1);
    k_gemm_mfma <<<grid_gm, gblk, 0, stream>>>(Wr, atf1, part);
    k_reduce_aff<<<grid_r4, blk, 0, stream>>>((const uint2*)part, afft, atf2);
    k_gemm_mfma <<<grid_gm, gblk, 0, stream>>>(Wi, atf2, part);
    k_combine   <<<grid_r4, blk, 0, stream>>>((const uint2*)part, afft, We, out);
}

// Round 17
// 161.399 us; speedup vs baseline: 1.0259x; 1.0259x over previous
//
#include <hip/hip_runtime.h>

#define SIDE 96
#define NN 9216            // SIDE*SIDE
#define BATCH 32
#define SPLIT 48           // split-K slices
#define SLICE (NN / SPLIT) // 192
#define NKT (SLICE / 16)   // 12 k-tiles (K=16 each) per slice
#define NJB (NN / 256)     // 36 j-blocks (256 cols per 8-wave block)
#define PSTRIDE ((size_t)NN * BATCH)   // bf16 elems per partial slice

typedef __attribute__((ext_vector_type(8)))  short  short8;
typedef __attribute__((ext_vector_type(16))) float  f32x16;
typedef __attribute__((ext_vector_type(4)))  unsigned int uintx4;

__device__ __forceinline__ float clamp01(float v) {
    return fminf(fmaxf(v, 0.0f), 1.0f);
}

__device__ __forceinline__ unsigned short f2bf(float f) {  // RNE fp32->bf16
    unsigned int u = __float_as_uint(f);
    return (unsigned short)((u + 0x7fffu + ((u >> 16) & 1u)) >> 16);
}

__device__ __forceinline__ unsigned int packbf2(float a, float b) {
    return (unsigned int)f2bf(a) | ((unsigned int)f2bf(b) << 16);
}

__device__ __forceinline__ float bf2f(unsigned short u) {
    return __uint_as_float(((unsigned int)u) << 16);
}

// atf[kt][l][i] = bf16(x[b][k]),  k = kt*16 + (l>>5)*8 + i,  b = l&31.
// Exactly the MFMA B-fragment order: lane l, k-slot ((l>>5), i).
__global__ __launch_bounds__(256) void k_prep_x(const float* __restrict__ x,
                                                unsigned short* __restrict__ atf) {
    int o = blockIdx.x * 256 + threadIdx.x;   // over NN*BATCH
    int kt = o >> 9, r = o & 511, l = r >> 3, i = r & 7;
    int b = l & 31, g = l >> 5;
    int k = kt * 16 + g * 8 + i;
    atf[o] = f2bf(x[(size_t)b * NN + k]);
}

// Partial GEMM via MFMA: part[s][j][b] (bf16) = sum_{k in slice s} at[k][b]*W[k][j]
// 8-wave (512-thread) block covers 256 consecutive j -> 1 KB contiguous W
// read per k-row per block (DRAM row-buffer locality), and all 8 waves share
// the identical atf dwordx4 loads via L1 broadcast.
// C/D mapping (verified): col(b)=lane&31, row(j)=(r&3)+8*(r>>2)+4*(lane>>5).
__global__ __launch_bounds__(512, 4) void k_gemm_mfma(
    const float* __restrict__ W,             // [NN][NN] k-major
    const unsigned short* __restrict__ atf,  // fragment-ordered activations
    unsigned short* __restrict__ part)       // [SPLIT][NN][BATCH] bf16
{
    const int tid  = threadIdx.x;
    const int wave = tid >> 6;               // 0..7
    const int lane = tid & 63;
    const int jl   = lane & 31;
    const int g    = lane >> 5;
    const int jb = blockIdx.x % NJB;
    const int s  = blockIdx.x / NJB;
    const int j  = jb * 256 + wave * 32 + jl;
    const size_t k0 = (size_t)s * SLICE;

    const float* wp = W + (k0 + (size_t)g * 8) * NN + j;
    const uintx4* bp = (const uintx4*)atf + (k0 >> 4) * 64 + lane;

    f32x16 acc;
#pragma unroll
    for (int e = 0; e < 16; ++e) acc[e] = 0.0f;

    float  wb[2][8];
    uintx4 bb[2];
#pragma unroll
    for (int i = 0; i < 8; ++i) wb[0][i] = wp[(size_t)i * NN];
    bb[0] = bp[0];

#pragma unroll
    for (int kt = 0; kt < NKT; ++kt) {
        const int cur = kt & 1, nxt = cur ^ 1;
        if (kt + 1 < NKT) {   // prefetch next k-tile (compile-time branch)
#pragma unroll
            for (int i = 0; i < 8; ++i)
                wb[nxt][i] = wp[((size_t)(kt + 1) * 16 + i) * NN];
            bb[nxt] = bp[(kt + 1) * 64];
        }
        uintx4 ap;
        ap[0] = packbf2(wb[cur][0], wb[cur][1]);
        ap[1] = packbf2(wb[cur][2], wb[cur][3]);
        ap[2] = packbf2(wb[cur][4], wb[cur][5]);
        ap[3] = packbf2(wb[cur][6], wb[cur][7]);
        short8 af = __builtin_bit_cast(short8, ap);
        short8 bf = __builtin_bit_cast(short8, bb[cur]);
        acc = __builtin_amdgcn_mfma_f32_32x32x16_bf16(af, bf, acc, 0, 0, 0);
    }

    unsigned short* pp = part + ((size_t)s * NN + (size_t)jb * 256 + wave * 32) * BATCH + jl;
#pragma unroll
    for (int r2 = 0; r2 < 16; ++r2) {
        int row = (r2 & 3) + 8 * (r2 >> 2) + 4 * g;
        pp[(size_t)row * BATCH] = f2bf(acc[r2]);
    }
}

// afft[k][b] = clamp01( sum_s part[s][k][b] ) (fp32), plus the same values
// re-emitted in MFMA B-fragment order (bf16) for the second GEMM.
// One thread handles 4 consecutive elements (same k, b0=4-aligned).
__global__ __launch_bounds__(256) void k_reduce_aff(
    const uint2* __restrict__ part,          // viewing bf16x4
    float* __restrict__ afft,
    unsigned short* __restrict__ atf2)
{
    int t = blockIdx.x * 256 + threadIdx.x;   // over NN*BATCH/4
    float v0 = 0.0f, v1 = 0.0f, v2 = 0.0f, v3 = 0.0f;
    for (int s = 0; s < SPLIT; ++s) {
        uint2 u = part[(size_t)s * (PSTRIDE / 4) + t];
        v0 += bf2f((unsigned short)(u.x & 0xffffu));
        v1 += bf2f((unsigned short)(u.x >> 16));
        v2 += bf2f((unsigned short)(u.y & 0xffffu));
        v3 += bf2f((unsigned short)(u.y >> 16));
    }
    v0 = clamp01(v0); v1 = clamp01(v1); v2 = clamp01(v2); v3 = clamp01(v3);
    float4 o = make_float4(v0, v1, v2, v3);
    ((float4*)afft)[t] = o;

    int k = t >> 3, b = (t & 7) * 4;
    int kt = k >> 4, g = (k >> 3) & 1, i = k & 7;
    size_t ob = (size_t)kt * 512 + (size_t)(g * 32 + b) * 8 + i;
    atf2[ob]      = f2bf(v0);
    atf2[ob + 8]  = f2bf(v1);
    atf2[ob + 16] = f2bf(v2);
    atf2[ob + 24] = f2bf(v3);
}

// Fused epilogue: reduce inhibitory bf16 partials (uint2 loads, 4 elems per
// thread), sparse excitatory gather (13 taps), combine. Thread = (j, b-quad).
__global__ __launch_bounds__(256) void k_combine(
    const uint2* __restrict__ part,           // [SPLIT][NN][BATCH] bf16, x4 view
    const float* __restrict__ afft,           // [NN][BATCH], clamped
    const float* __restrict__ We,             // [NN][NN]
    float* __restrict__ out)                  // [BATCH][NN]
{
    int t = blockIdx.x * 256 + threadIdx.x;   // over NN*BATCH/4
    int j  = t >> 3;
    int bq = t & 7;                           // batch quad: b = 4bq..4bq+3

    float i0 = 0.0f, i1 = 0.0f, i2 = 0.0f, i3 = 0.0f;
    for (int s = 0; s < SPLIT; ++s) {
        uint2 u = part[(size_t)s * (PSTRIDE / 4) + t];
        i0 += bf2f((unsigned short)(u.x & 0xffffu));
        i1 += bf2f((unsigned short)(u.x >> 16));
        i2 += bf2f((unsigned short)(u.y & 0xffffu));
        i3 += bf2f((unsigned short)(u.y >> 16));
    }
    i0 = clamp01(i0); i1 = clamp01(i1); i2 = clamp01(i2); i3 = clamp01(i3);

    int mx = j / SIDE;
    int my = j - mx * SIDE;

    const int dxs[13] = {-2,-1,-1,-1, 0, 0, 0, 0, 0, 1, 1, 1, 2};
    const int dys[13] = { 0,-1, 0, 1,-2,-1, 0, 1, 2,-1, 0, 1, 0};

    float e0 = 0.0f, e1 = 0.0f, e2 = 0.0f, e3 = 0.0f;
#pragma unroll
    for (int tp = 0; tp < 13; ++tp) {
        int xx = mx + dxs[tp];
        int yy = my + dys[tp];
        if ((unsigned)xx < SIDE && (unsigned)yy < SIDE) {
            int i = xx * SIDE + yy;
            float w = We[(size_t)i * NN + j];
            float4 av = ((const float4*)afft)[(size_t)i * 8 + bq];
            e0 = fmaf(av.x, w, e0);
            e1 = fmaf(av.y, w, e1);
            e2 = fmaf(av.z, w, e2);
            e3 = fmaf(av.w, w, e3);
        }
    }
    e0 = clamp01(e0); e1 = clamp01(e1); e2 = clamp01(e2); e3 = clamp01(e3);

    float4 a = ((const float4*)afft)[t];
    out[(size_t)(4 * bq + 0) * NN + j] = clamp01(a.x + 0.2f * e0 - 0.4f * i0);
    out[(size_t)(4 * bq + 1) * NN + j] = clamp01(a.y + 0.2f * e1 - 0.4f * i1);
    out[(size_t)(4 * bq + 2) * NN + j] = clamp01(a.z + 0.2f * e2 - 0.4f * i2);
    out[(size_t)(4 * bq + 3) * NN + j] = clamp01(a.w + 0.2f * e3 - 0.4f * i3);
}

extern "C" void kernel_launch(void* const* d_in, const int* in_sizes, int n_in,
                              void* d_out, int out_size, void* d_ws, size_t ws_size,
                              hipStream_t stream) {
    const float* x  = (const float*)d_in[0];  // [32][9216]
    const float* Wr = (const float*)d_in[1];  // [9216][9216]
    const float* We = (const float*)d_in[2];  // [9216][9216] sparse (radius 2)
    const float* Wi = (const float*)d_in[3];  // [9216][9216]
    float* out = (float*)d_out;               // [32][9216]

    unsigned short* atf1 = (unsigned short*)d_ws;        // NN*32 bf16 (frag order)
    float* afft = (float*)(atf1 + (size_t)NN * BATCH);   // NN*32 fp32
    unsigned short* atf2 = (unsigned short*)(afft + (size_t)NN * BATCH);
    unsigned short* part = atf2 + (size_t)NN * BATCH;    // SPLIT*NN*32 bf16 = 28.3 MB

    dim3 gblk(512);
    dim3 blk(256);
    dim3 grid_eb(NN * BATCH / 256);        // 1152
    dim3 grid_r4(NN * BATCH / 4 / 256);    // 288
    dim3 grid_gm(NJB * SPLIT);             // 1728

    k_prep_x    <<<grid_eb, blk, 0, stream>>>(x, atf1);
    k_gemm_mfma <<<grid_gm, gblk, 0, stream>>>(Wr, atf1, part);
    k_reduce_aff<<<grid_r4, blk, 0, stream>>>((const uint2*)part, afft, atf2);
    k_gemm_mfma <<<grid_gm, gblk, 0, stream>>>(Wi, atf2, part);
    k_combine   <<<grid_r4, blk, 0, stream>>>((const uint2*)part, afft, We, out);
}